// Round 1
// baseline (414.621 us; speedup 1.0000x reference)
//
#include <hip/hip_runtime.h>
#include <hip/hip_bf16.h>

#define NROWS 4096
#define NLAB  2048

typedef __attribute__((ext_vector_type(8))) short short8;
typedef __attribute__((ext_vector_type(4))) float f32x4;

__device__ __forceinline__ unsigned short f2bf(float x) {
  unsigned int u = __float_as_uint(x);
  unsigned int r = u + 0x7fffu + ((u >> 16) & 1u);   // RNE, no NaN in data
  return (unsigned short)(r >> 16);
}

// ---- ranks of labels (global stable sort by counting) + scatter sorted values ----
__global__ __launch_bounds__(256) void rank_kernel(const float* __restrict__ labels,
                                                   int* __restrict__ rankv,
                                                   float* __restrict__ ssorted) {
  __shared__ float L[NLAB];
  const int tid = threadIdx.x;
  for (int t = tid; t < NLAB; t += 256) L[t] = labels[t];
  __syncthreads();
  const int i = blockIdx.x * 256 + tid;          // i in [0,4096)
  const float a = L[i & (NLAB - 1)];
  int cnt = 0;
  for (int j = 0; j < NLAB; ++j) {
    float l = L[j];
    if (l < a) cnt += 2;                          // both tiled copies
    else if (l == a) cnt += (j < i) + (j + NLAB < i);  // stable tie-break by index
  }
  rankv[i] = cnt;
  ssorted[cnt] = a;
}

// ---- fp32 row squared norms ----
__global__ __launch_bounds__(256) void r_kernel(const float* __restrict__ z1,
                                                const float* __restrict__ z2,
                                                float* __restrict__ rout) {
  const int lane = threadIdx.x & 63, wid = threadIdx.x >> 6;
  const int row = blockIdx.x * 4 + wid;
  const float* src = (row < NLAB) ? (z1 + (size_t)row * 256)
                                  : (z2 + (size_t)(row - NLAB) * 256);
  float4 v = ((const float4*)src)[lane];          // 64 lanes x 4 = 256
  float ss = v.x * v.x + v.y * v.y + v.z * v.z + v.w * v.w;
  #pragma unroll
  for (int off = 32; off > 0; off >>= 1) ss += __shfl_down(ss, off, 64);
  if (lane == 0) rout[row] = ss;
}

// ---- fp32 -> bf16 feature matrix ----
__global__ __launch_bounds__(256) void conv_kernel(const float* __restrict__ z1,
                                                   const float* __restrict__ z2,
                                                   unsigned short* __restrict__ Fb) {
  const int idx4 = blockIdx.x * 256 + threadIdx.x;  // float4 index, 262144 total
  const int row = idx4 >> 6;                        // 64 float4 per 256-elem row
  float4 v = (row < NLAB) ? ((const float4*)z1)[idx4]
                          : ((const float4*)z2)[idx4 - NLAB * 64];
  ushort4 o;
  o.x = f2bf(v.x); o.y = f2bf(v.y); o.z = f2bf(v.z); o.w = f2bf(v.w);
  ((ushort4*)Fb)[idx4] = o;
}

// ---- G = F * F^T (bf16 MFMA, global-direct; F is L2-resident) ----
__global__ __launch_bounds__(256) void gemm_kernel(const unsigned short* __restrict__ Fb,
                                                   float* __restrict__ Gslab, int row0) {
  const int lane = threadIdx.x & 63, wid = threadIdx.x >> 6;
  const int wm = wid >> 1, wn = wid & 1;            // 4 waves -> 2x2 of 32x32
  const int m0 = row0 + blockIdx.x * 64 + wm * 32;
  const int n0 = blockIdx.y * 64 + wn * 32;
  const int r16 = lane & 15, kg = lane >> 4;
  const f32x4 z = {0.f, 0.f, 0.f, 0.f};
  f32x4 acc00 = z, acc01 = z, acc10 = z, acc11 = z;
  const unsigned short* pa0 = Fb + (size_t)(m0 + r16) * 256 + kg * 8;
  const unsigned short* pa1 = pa0 + 16 * 256;
  const unsigned short* pb0 = Fb + (size_t)(n0 + r16) * 256 + kg * 8;
  const unsigned short* pb1 = pb0 + 16 * 256;
  #pragma unroll
  for (int ks = 0; ks < 8; ++ks) {                  // K = 256 = 8 x 32
    const int k0 = ks * 32;
    short8 a0 = *(const short8*)(pa0 + k0);
    short8 a1 = *(const short8*)(pa1 + k0);
    short8 b0 = *(const short8*)(pb0 + k0);
    short8 b1 = *(const short8*)(pb1 + k0);
    acc00 = __builtin_amdgcn_mfma_f32_16x16x32_bf16(a0, b0, acc00, 0, 0, 0);
    acc01 = __builtin_amdgcn_mfma_f32_16x16x32_bf16(a0, b1, acc01, 0, 0, 0);
    acc10 = __builtin_amdgcn_mfma_f32_16x16x32_bf16(a1, b0, acc10, 0, 0, 0);
    acc11 = __builtin_amdgcn_mfma_f32_16x16x32_bf16(a1, b1, acc11, 0, 0, 0);
  }
  // C/D layout (m89-verified): col = lane&15, row = (lane>>4)*4 + reg
  const int crow = kg * 4, ccol = r16;
  const int lm = blockIdx.x * 64 + wm * 32;         // slab-local row base
  float* g00 = Gslab + (size_t)(lm + crow) * NROWS + n0 + ccol;
  #pragma unroll
  for (int rr = 0; rr < 4; ++rr) {
    g00[(size_t)rr * NROWS]              = acc00[rr];
    g00[(size_t)rr * NROWS + 16]         = acc01[rr];
    g00[(size_t)(16 + rr) * NROWS]       = acc10[rr];
    g00[(size_t)(16 + rr) * NROWS + 16]  = acc11[rr];
  }
}

// ---- per-row: w scatter by rank, prefix sum, two-tail binary searches, log-denoms ----
__global__ __launch_bounds__(256) void main_kernel(const float* __restrict__ Gslab,
                                                   const float* __restrict__ r,
                                                   const float* __restrict__ labels,
                                                   const float* __restrict__ ssorted,
                                                   const int* __restrict__ rankv,
                                                   int row0, double* __restrict__ acc) {
  __shared__ float s[NROWS];
  __shared__ float P[NROWS];
  __shared__ float wsum[4];
  __shared__ float fin[4];
  const int tid = threadIdx.x;
  const int i = row0 + blockIdx.x;
  const float* Grow = Gslab + (size_t)blockIdx.x * NROWS;
  for (int t = tid; t < NROWS; t += 256) s[t] = ssorted[t];
  const float a = labels[i & (NLAB - 1)];
  const float ri = r[i];
  float losum = 0.f;
  // pass 1: logits -> weights, scatter into sorted-label positions
  for (int t = tid; t < NROWS; t += 256) {
    float w = 0.f;
    if (t != i) {
      float sq = fmaxf(ri + r[t] - 2.f * Grow[t], 0.f);
      float lo = -0.5f * sqrtf(sq);                 // -dist / TEMPERATURE(=2)
      losum += lo;
      w = expf(lo);                                 // unshifted: shift cancels exactly
    }
    P[rankv[t]] = w;
  }
  __syncthreads();
  // in-place inclusive prefix sum over P[4096], 16 elems/thread
  const int base = tid * 16;
  float run = 0.f;
  #pragma unroll
  for (int u = 0; u < 16; ++u) { run += P[base + u]; P[base + u] = run; }
  const int lane = tid & 63, wid = tid >> 6;
  float x = run;
  #pragma unroll
  for (int off = 1; off < 64; off <<= 1) {
    float y = __shfl_up(x, off, 64);
    if (lane >= off) x += y;
  }
  if (lane == 63) wsum[wid] = x;
  __syncthreads();
  float woff = 0.f;
  for (int wle = 0; wle < wid; ++wle) woff += wsum[wle];
  const float excl = woff + x - run;
  #pragma unroll
  for (int u = 0; u < 16; ++u) P[base + u] += excl;
  const float Ptot = wsum[0] + wsum[1] + wsum[2] + wsum[3];
  __syncthreads();
  // pL = last q with s[q] <= a (a is present in s, so pL >= 0)
  int pL = -1;
  { int lo = 0, hi = NROWS - 1;
    while (lo <= hi) { int m = (lo + hi) >> 1;
      if (s[m] <= a) { pL = m; lo = m + 1; } else hi = m - 1; } }
  // pass 2: denom[i,k] = left-tail prefix + right-tail suffix (exact fp tie semantics)
  float logden = 0.f;
  for (int t = tid; t < NROWS; t += 256) {
    if (t == i) continue;
    const float v = fabsf(a - labels[t & (NLAB - 1)]);
    int qL = -1;
    { int lo = 0, hi = pL;
      while (lo <= hi) { int m = (lo + hi) >> 1;
        if (a - s[m] >= v) { qL = m; lo = m + 1; } else hi = m - 1; } }
    int qR = NROWS;
    { int lo = pL + 1, hi = NROWS - 1;
      while (lo <= hi) { int m = (lo + hi) >> 1;
        if (s[m] - a >= v) { qR = m; hi = m - 1; } else lo = m + 1; } }
    float den = (qL >= 0 ? P[qL] : 0.f);
    if (qR < NROWS) den += Ptot - (qR > 0 ? P[qR - 1] : 0.f);
    logden += logf(den);
  }
  // block reduce -> fp64 atomics
  #pragma unroll
  for (int off = 32; off > 0; off >>= 1) {
    losum  += __shfl_down(losum, off, 64);
    logden += __shfl_down(logden, off, 64);
  }
  if (lane == 0) { wsum[wid] = losum; fin[wid] = logden; }
  __syncthreads();
  if (tid == 0) {
    double L = 0.0, D = 0.0;
    for (int w = 0; w < 4; ++w) { L += (double)wsum[w]; D += (double)fin[w]; }
    atomicAdd(&acc[0], L);
    atomicAdd(&acc[1], D);
  }
}

__global__ void final_kernel(const double* __restrict__ acc, float* __restrict__ out) {
  // loss = (sum log denom - sum lo) / (n*(n-1))
  out[0] = (float)((acc[1] - acc[0]) / 16773120.0);
}

extern "C" void kernel_launch(void* const* d_in, const int* in_sizes, int n_in,
                              void* d_out, int out_size, void* d_ws, size_t ws_size,
                              hipStream_t stream) {
  (void)in_sizes; (void)n_in; (void)out_size;
  const float* z1     = (const float*)d_in[0];
  const float* z2     = (const float*)d_in[1];
  const float* labels = (const float*)d_in[2];
  float* out = (float*)d_out;

  char* ws = (char*)d_ws;
  double* acc            = (double*)ws;                       // 16 B
  float*  ssorted        = (float*)(ws + 1024);               // 16 KB
  int*    rankv          = (int*)(ws + 1024 + 16384);         // 16 KB
  float*  rbuf           = (float*)(ws + 1024 + 2 * 16384);   // 16 KB
  unsigned short* Fb     = (unsigned short*)(ws + 65536);     // 2 MB bf16 features
  const size_t G_off = (size_t)4 << 20;
  float* G = (float*)(ws + G_off);

  // adaptive slabbing of G through the workspace
  size_t rows_cap = (ws_size > G_off + (size_t)64 * NROWS * 4)
                        ? (ws_size - G_off) / ((size_t)NROWS * 4) : 64;
  int R = (int)((rows_cap / 64) * 64);
  if (R < 64) R = 64;
  if (R > NROWS) R = NROWS;

  hipMemsetAsync(acc, 0, 16, stream);
  rank_kernel<<<NROWS / 256, 256, 0, stream>>>(labels, rankv, ssorted);
  r_kernel<<<NROWS / 4, 256, 0, stream>>>(z1, z2, rbuf);
  conv_kernel<<<(NROWS * 64) / 256, 256, 0, stream>>>(z1, z2, Fb);
  for (int row0 = 0; row0 < NROWS; row0 += R) {
    int rows = NROWS - row0; if (rows > R) rows = R;
    gemm_kernel<<<dim3(rows / 64, NROWS / 64), 256, 0, stream>>>(Fb, G, row0);
    main_kernel<<<rows, 256, 0, stream>>>(G, rbuf, labels, ssorted, rankv, row0, acc);
  }
  final_kernel<<<1, 1, 0, stream>>>(acc, out);
}

// Round 2
// 324.950 us; speedup vs baseline: 1.2760x; 1.2760x over previous
//
#include <hip/hip_runtime.h>
#include <hip/hip_bf16.h>

#define NROWS 4096
#define NLAB  2048
#define PIDX(p) ((p) + ((p) >> 5))   // LDS swizzle: lane-stride-16 access -> 2-way (free)

typedef __attribute__((ext_vector_type(8))) short short8;
typedef __attribute__((ext_vector_type(4))) float f32x4;

__device__ __forceinline__ unsigned short f2bf(float x) {
  unsigned int u = __float_as_uint(x);
  unsigned int r = u + 0x7fffu + ((u >> 16) & 1u);   // RNE, no NaN in data
  return (unsigned short)(r >> 16);
}

// ---- ranks of labels: wave-per-element counting sort (1024 blocks) ----
__global__ __launch_bounds__(256) void rank_kernel(const float* __restrict__ labels,
                                                   int* __restrict__ rankv,
                                                   float* __restrict__ ssorted) {
  __shared__ float L[NLAB];
  const int tid = threadIdx.x;
  for (int t = tid; t < NLAB; t += 256) L[t] = labels[t];
  __syncthreads();
  const int lane = tid & 63, wid = tid >> 6;
  const int i = blockIdx.x * 4 + wid;            // element in [0,4096)
  const float a = L[i & (NLAB - 1)];
  int cnt = 0;
  #pragma unroll 4
  for (int jj = 0; jj < NLAB / 64; ++jj) {
    const int j = jj * 64 + lane;
    const float l = L[j];
    if (l < a) cnt += 2;                          // both tiled copies
    else if (l == a) cnt += (j < i) + (j + NLAB < i);  // stable tie-break
  }
  #pragma unroll
  for (int off = 32; off > 0; off >>= 1) cnt += __shfl_down(cnt, off, 64);
  if (lane == 0) { rankv[i] = cnt; ssorted[cnt] = a; }
}

// ---- fused: fp32 -> bf16 features + row squared norms (wave per row) ----
__global__ __launch_bounds__(256) void convr_kernel(const float* __restrict__ z1,
                                                    const float* __restrict__ z2,
                                                    unsigned short* __restrict__ Fb,
                                                    float* __restrict__ rout) {
  const int lane = threadIdx.x & 63, wid = threadIdx.x >> 6;
  const int row = blockIdx.x * 4 + wid;
  const float* src = (row < NLAB) ? (z1 + (size_t)row * 256)
                                  : (z2 + (size_t)(row - NLAB) * 256);
  float4 v = ((const float4*)src)[lane];          // 64 lanes x 4 = 256
  ushort4 o;
  o.x = f2bf(v.x); o.y = f2bf(v.y); o.z = f2bf(v.z); o.w = f2bf(v.w);
  ((ushort4*)Fb)[(size_t)row * 64 + lane] = o;
  float ss = v.x * v.x + v.y * v.y + v.z * v.z + v.w * v.w;
  #pragma unroll
  for (int off = 32; off > 0; off >>= 1) ss += __shfl_down(ss, off, 64);
  if (lane == 0) rout[row] = ss;
}

// ---- G = F * F^T (bf16 MFMA, global-direct; F is L2-resident) ----
__global__ __launch_bounds__(256) void gemm_kernel(const unsigned short* __restrict__ Fb,
                                                   float* __restrict__ Gslab, int row0) {
  const int lane = threadIdx.x & 63, wid = threadIdx.x >> 6;
  const int wm = wid >> 1, wn = wid & 1;            // 4 waves -> 2x2 of 32x32
  const int m0 = row0 + blockIdx.x * 64 + wm * 32;
  const int n0 = blockIdx.y * 64 + wn * 32;
  const int r16 = lane & 15, kg = lane >> 4;
  const f32x4 z = {0.f, 0.f, 0.f, 0.f};
  f32x4 acc00 = z, acc01 = z, acc10 = z, acc11 = z;
  const unsigned short* pa0 = Fb + (size_t)(m0 + r16) * 256 + kg * 8;
  const unsigned short* pa1 = pa0 + 16 * 256;
  const unsigned short* pb0 = Fb + (size_t)(n0 + r16) * 256 + kg * 8;
  const unsigned short* pb1 = pb0 + 16 * 256;
  #pragma unroll
  for (int ks = 0; ks < 8; ++ks) {                  // K = 256 = 8 x 32
    const int k0 = ks * 32;
    short8 a0 = *(const short8*)(pa0 + k0);
    short8 a1 = *(const short8*)(pa1 + k0);
    short8 b0 = *(const short8*)(pb0 + k0);
    short8 b1 = *(const short8*)(pb1 + k0);
    acc00 = __builtin_amdgcn_mfma_f32_16x16x32_bf16(a0, b0, acc00, 0, 0, 0);
    acc01 = __builtin_amdgcn_mfma_f32_16x16x32_bf16(a0, b1, acc01, 0, 0, 0);
    acc10 = __builtin_amdgcn_mfma_f32_16x16x32_bf16(a1, b0, acc10, 0, 0, 0);
    acc11 = __builtin_amdgcn_mfma_f32_16x16x32_bf16(a1, b1, acc11, 0, 0, 0);
  }
  // C/D layout (m89-verified): col = lane&15, row = (lane>>4)*4 + reg
  const int crow = kg * 4, ccol = r16;
  const int lm = blockIdx.x * 64 + wm * 32;         // slab-local row base
  float* g00 = Gslab + (size_t)(lm + crow) * NROWS + n0 + ccol;
  #pragma unroll
  for (int rr = 0; rr < 4; ++rr) {
    g00[(size_t)rr * NROWS]              = acc00[rr];
    g00[(size_t)rr * NROWS + 16]         = acc01[rr];
    g00[(size_t)(16 + rr) * NROWS]       = acc10[rr];
    g00[(size_t)(16 + rr) * NROWS + 16]  = acc11[rr];
  }
}

// ---- per-row: weights by rank, swizzled prefix sum, monotone two-pointer denoms ----
__global__ __launch_bounds__(256) void main_kernel(const float* __restrict__ Gslab,
                                                   const float* __restrict__ r,
                                                   const float* __restrict__ labels,
                                                   const float* __restrict__ ssorted,
                                                   const int* __restrict__ rankv,
                                                   int row0, double* __restrict__ acc) {
  __shared__ float s[NROWS];
  __shared__ float P[NROWS + NROWS / 32];           // swizzled prefix sums
  __shared__ float wsum[4];
  __shared__ float fin[4];
  const int tid = threadIdx.x;
  const int i = row0 + blockIdx.x;
  const float* __restrict__ Grow = Gslab + (size_t)blockIdx.x * NROWS;
  for (int t = tid; t < NROWS; t += 256) s[t] = ssorted[t];
  const float a = labels[i & (NLAB - 1)];
  const float ri = r[i];
  const int prank = rankv[i];                       // sorted position of element i
  float losum = 0.f;
  // pass 1: logits -> weights, scatter into sorted positions (vectorized loads)
  #pragma unroll
  for (int it = 0; it < 4; ++it) {
    const int t4 = it * 256 + tid;
    const float4 g  = ((const float4*)Grow)[t4];
    const float4 rt = ((const float4*)r)[t4];
    const int4  rk  = ((const int4*)rankv)[t4];
    const int t = t4 * 4;
    {
      float w = 0.f;
      if (t != i) { float sq = fmaxf(ri + rt.x - 2.f * g.x, 0.f);
        float lo = -0.5f * __builtin_amdgcn_sqrtf(sq); losum += lo; w = __expf(lo); }
      P[PIDX(rk.x)] = w;
    }
    {
      float w = 0.f;
      if (t + 1 != i) { float sq = fmaxf(ri + rt.y - 2.f * g.y, 0.f);
        float lo = -0.5f * __builtin_amdgcn_sqrtf(sq); losum += lo; w = __expf(lo); }
      P[PIDX(rk.y)] = w;
    }
    {
      float w = 0.f;
      if (t + 2 != i) { float sq = fmaxf(ri + rt.z - 2.f * g.z, 0.f);
        float lo = -0.5f * __builtin_amdgcn_sqrtf(sq); losum += lo; w = __expf(lo); }
      P[PIDX(rk.z)] = w;
    }
    {
      float w = 0.f;
      if (t + 3 != i) { float sq = fmaxf(ri + rt.w - 2.f * g.w, 0.f);
        float lo = -0.5f * __builtin_amdgcn_sqrtf(sq); losum += lo; w = __expf(lo); }
      P[PIDX(rk.w)] = w;
    }
  }
  __syncthreads();
  // inclusive prefix sum over P[4096]: 16 contiguous elems/thread (swizzled -> 2-way)
  const int base = tid * 16;
  const int pbase = PIDX(base);                     // run of 16 is contiguous in phys
  float run = 0.f;
  #pragma unroll
  for (int u = 0; u < 16; ++u) { run += P[pbase + u]; P[pbase + u] = run; }
  const int lane = tid & 63, wid = tid >> 6;
  float x = run;
  #pragma unroll
  for (int off = 1; off < 64; off <<= 1) {
    float y = __shfl_up(x, off, 64);
    if (lane >= off) x += y;
  }
  if (lane == 63) wsum[wid] = x;
  __syncthreads();
  float woff = 0.f;
  for (int w = 0; w < wid; ++w) woff += wsum[w];
  const float excl = woff + x - run;
  #pragma unroll
  for (int u = 0; u < 16; ++u) P[pbase + u] += excl;
  const float Ptot = wsum[0] + wsum[1] + wsum[2] + wsum[3];
  __syncthreads();
  // pL = last q with s[q] <= a (a present -> pL >= 0); uniform across block
  int pL = -1;
  { int lo = 0, hi = NROWS - 1;
    while (lo <= hi) { int m = (lo + hi) >> 1;
      if (s[m] <= a) { pL = m; lo = m + 1; } else hi = m - 1; } }
  // pass 2: thread owns sorted positions [p0, p0+15]; monotone pointers per side
  float logden = 0.f, prod = 1.f;
  int pm = 0;
  const int p0 = tid * 16, p1 = p0 + 15;
  // ---- left segment (p <= pL): v = a - s[p], non-increasing in p ----
  if (p0 <= pL) {
    const int lend = (p1 < pL) ? p1 : pL;
    float v = a - s[p0];
    int eL = p0;                                    // last q in [0,pL] with a-s[q] >= v
    { int lo = p0 + 1, hi = pL;
      while (lo <= hi) { int m = (lo + hi) >> 1;
        if (a - s[m] >= v) { eL = m; lo = m + 1; } else hi = m - 1; } }
    int rR = NROWS;                                 // first q in [pL+1,n) with s[q]-a >= v
    { int lo = pL + 1, hi = NROWS - 1;
      while (lo <= hi) { int m = (lo + hi) >> 1;
        if (s[m] - a >= v) { rR = m; hi = m - 1; } else lo = m + 1; } }
    for (int p = p0; p <= lend; ++p) {
      v = a - s[p];
      while (eL < pL && a - s[eL + 1] >= v) ++eL;
      while (rR > pL + 1 && s[rR - 1] - a >= v) --rR;
      if (p != prank) {
        float den = P[PIDX(eL)];
        if (rR < NROWS) den += Ptot - P[PIDX(rR - 1)];
        prod *= den;
        if (++pm == 4) { logden += __logf(prod); prod = 1.f; pm = 0; }
      }
    }
  }
  // ---- right segment (p > pL): v = s[p] - a, non-decreasing in p ----
  if (p1 > pL) {
    const int rstart = (p0 > pL + 1) ? p0 : pL + 1;
    float v = s[rstart] - a;
    int qR = rstart;                                // first q in [pL+1,n) with s[q]-a >= v
    { int lo = pL + 1, hi = rstart - 1;
      while (lo <= hi) { int m = (lo + hi) >> 1;
        if (s[m] - a >= v) { qR = m; hi = m - 1; } else lo = m + 1; } }
    int qL = -1;                                    // last q in [0,pL] with a-s[q] >= v
    { int lo = 0, hi = pL;
      while (lo <= hi) { int m = (lo + hi) >> 1;
        if (a - s[m] >= v) { qL = m; lo = m + 1; } else hi = m - 1; } }
    for (int p = rstart; p <= p1; ++p) {
      v = s[p] - a;
      while (s[qR] - a < v) ++qR;                   // bounded by q = p (satisfies)
      while (qL >= 0 && a - s[qL] < v) --qL;
      float den = Ptot - P[PIDX(qR - 1)];
      if (qL >= 0) den += P[PIDX(qL)];
      prod *= den;
      if (++pm == 4) { logden += __logf(prod); prod = 1.f; pm = 0; }
    }
  }
  if (pm > 0) logden += __logf(prod);
  // block reduce -> fp64 atomics
  #pragma unroll
  for (int off = 32; off > 0; off >>= 1) {
    losum  += __shfl_down(losum, off, 64);
    logden += __shfl_down(logden, off, 64);
  }
  if (lane == 0) { wsum[wid] = losum; fin[wid] = logden; }
  __syncthreads();
  if (tid == 0) {
    double L = 0.0, D = 0.0;
    for (int w = 0; w < 4; ++w) { L += (double)wsum[w]; D += (double)fin[w]; }
    atomicAdd(&acc[0], L);
    atomicAdd(&acc[1], D);
  }
}

__global__ void final_kernel(const double* __restrict__ acc, float* __restrict__ out) {
  // loss = (sum log denom - sum lo) / (n*(n-1))
  out[0] = (float)((acc[1] - acc[0]) / 16773120.0);
}

extern "C" void kernel_launch(void* const* d_in, const int* in_sizes, int n_in,
                              void* d_out, int out_size, void* d_ws, size_t ws_size,
                              hipStream_t stream) {
  (void)in_sizes; (void)n_in; (void)out_size;
  const float* z1     = (const float*)d_in[0];
  const float* z2     = (const float*)d_in[1];
  const float* labels = (const float*)d_in[2];
  float* out = (float*)d_out;

  char* ws = (char*)d_ws;
  double* acc            = (double*)ws;                       // 16 B
  float*  ssorted        = (float*)(ws + 1024);               // 16 KB
  int*    rankv          = (int*)(ws + 1024 + 16384);         // 16 KB
  float*  rbuf           = (float*)(ws + 1024 + 2 * 16384);   // 16 KB
  unsigned short* Fb     = (unsigned short*)(ws + 65536);     // 2 MB bf16 features
  const size_t G_off = (size_t)4 << 20;
  float* G = (float*)(ws + G_off);

  // adaptive slabbing of G through the workspace
  size_t rows_cap = (ws_size > G_off + (size_t)64 * NROWS * 4)
                        ? (ws_size - G_off) / ((size_t)NROWS * 4) : 64;
  int R = (int)((rows_cap / 64) * 64);
  if (R < 64) R = 64;
  if (R > NROWS) R = NROWS;

  hipMemsetAsync(acc, 0, 16, stream);
  rank_kernel<<<NROWS / 4, 256, 0, stream>>>(labels, rankv, ssorted);
  convr_kernel<<<NROWS / 4, 256, 0, stream>>>(z1, z2, Fb, rbuf);
  for (int row0 = 0; row0 < NROWS; row0 += R) {
    int rows = NROWS - row0; if (rows > R) rows = R;
    gemm_kernel<<<dim3(rows / 64, NROWS / 64), 256, 0, stream>>>(Fb, G, row0);
    main_kernel<<<rows, 256, 0, stream>>>(G, rbuf, labels, ssorted, rankv, row0, acc);
  }
  final_kernel<<<1, 1, 0, stream>>>(acc, out);
}

// Round 3
// 246.896 us; speedup vs baseline: 1.6793x; 1.3161x over previous
//
#include <hip/hip_runtime.h>
#include <hip/hip_bf16.h>

#define NROWS 4096
#define NLAB  2048
#define PIDX(p) ((p) + ((p) >> 5))   // LDS swizzle: stride-8/16 lane access -> 2-way (free)
#define FMAXV 3.402823466e+38f

typedef __attribute__((ext_vector_type(8))) short short8;
typedef __attribute__((ext_vector_type(4))) float f32x4;

__device__ __forceinline__ unsigned short f2bf(float x) {
  unsigned int u = __float_as_uint(x);
  unsigned int r = u + 0x7fffu + ((u >> 16) & 1u);   // RNE, no NaN in data
  return (unsigned short)(r >> 16);
}

// ---- ranks of labels: wave-per-element counting sort (1024 blocks) ----
__global__ __launch_bounds__(256) void rank_kernel(const float* __restrict__ labels,
                                                   int* __restrict__ rankv,
                                                   float* __restrict__ ssorted) {
  __shared__ float L[NLAB];
  const int tid = threadIdx.x;
  for (int t = tid; t < NLAB; t += 256) L[t] = labels[t];
  __syncthreads();
  const int lane = tid & 63, wid = tid >> 6;
  const int i = blockIdx.x * 4 + wid;            // element in [0,4096)
  const float a = L[i & (NLAB - 1)];
  int cnt = 0;
  #pragma unroll 4
  for (int jj = 0; jj < NLAB / 64; ++jj) {
    const int j = jj * 64 + lane;
    const float l = L[j];
    if (l < a) cnt += 2;                          // both tiled copies
    else if (l == a) cnt += (j < i) + (j + NLAB < i);  // stable tie-break
  }
  #pragma unroll
  for (int off = 32; off > 0; off >>= 1) cnt += __shfl_down(cnt, off, 64);
  if (lane == 0) { rankv[i] = cnt; ssorted[cnt] = a; }
}

// ---- fused: fp32 -> bf16 features + row squared norms (wave per row) ----
__global__ __launch_bounds__(256) void convr_kernel(const float* __restrict__ z1,
                                                    const float* __restrict__ z2,
                                                    unsigned short* __restrict__ Fb,
                                                    float* __restrict__ rout) {
  const int lane = threadIdx.x & 63, wid = threadIdx.x >> 6;
  const int row = blockIdx.x * 4 + wid;
  const float* src = (row < NLAB) ? (z1 + (size_t)row * 256)
                                  : (z2 + (size_t)(row - NLAB) * 256);
  float4 v = ((const float4*)src)[lane];          // 64 lanes x 4 = 256
  ushort4 o;
  o.x = f2bf(v.x); o.y = f2bf(v.y); o.z = f2bf(v.z); o.w = f2bf(v.w);
  ((ushort4*)Fb)[(size_t)row * 64 + lane] = o;
  float ss = v.x * v.x + v.y * v.y + v.z * v.z + v.w * v.w;
  #pragma unroll
  for (int off = 32; off > 0; off >>= 1) ss += __shfl_down(ss, off, 64);
  if (lane == 0) rout[row] = ss;
}

// ---- G = F * F^T (bf16 MFMA, global-direct; F is L2-resident) ----
__global__ __launch_bounds__(256) void gemm_kernel(const unsigned short* __restrict__ Fb,
                                                   float* __restrict__ Gslab, int row0) {
  const int lane = threadIdx.x & 63, wid = threadIdx.x >> 6;
  const int wm = wid >> 1, wn = wid & 1;            // 4 waves -> 2x2 of 32x32
  const int m0 = row0 + blockIdx.x * 64 + wm * 32;
  const int n0 = blockIdx.y * 64 + wn * 32;
  const int r16 = lane & 15, kg = lane >> 4;
  const f32x4 z = {0.f, 0.f, 0.f, 0.f};
  f32x4 acc00 = z, acc01 = z, acc10 = z, acc11 = z;
  const unsigned short* pa0 = Fb + (size_t)(m0 + r16) * 256 + kg * 8;
  const unsigned short* pa1 = pa0 + 16 * 256;
  const unsigned short* pb0 = Fb + (size_t)(n0 + r16) * 256 + kg * 8;
  const unsigned short* pb1 = pb0 + 16 * 256;
  #pragma unroll
  for (int ks = 0; ks < 8; ++ks) {                  // K = 256 = 8 x 32
    const int k0 = ks * 32;
    short8 a0 = *(const short8*)(pa0 + k0);
    short8 a1 = *(const short8*)(pa1 + k0);
    short8 b0 = *(const short8*)(pb0 + k0);
    short8 b1 = *(const short8*)(pb1 + k0);
    acc00 = __builtin_amdgcn_mfma_f32_16x16x32_bf16(a0, b0, acc00, 0, 0, 0);
    acc01 = __builtin_amdgcn_mfma_f32_16x16x32_bf16(a0, b1, acc01, 0, 0, 0);
    acc10 = __builtin_amdgcn_mfma_f32_16x16x32_bf16(a1, b0, acc10, 0, 0, 0);
    acc11 = __builtin_amdgcn_mfma_f32_16x16x32_bf16(a1, b1, acc11, 0, 0, 0);
  }
  // C/D layout (m89-verified): col = lane&15, row = (lane>>4)*4 + reg
  const int crow = kg * 4, ccol = r16;
  const int lm = blockIdx.x * 64 + wm * 32;         // slab-local row base
  float* g00 = Gslab + (size_t)(lm + crow) * NROWS + n0 + ccol;
  #pragma unroll
  for (int rr = 0; rr < 4; ++rr) {
    g00[(size_t)rr * NROWS]              = acc00[rr];
    g00[(size_t)rr * NROWS + 16]         = acc01[rr];
    g00[(size_t)(16 + rr) * NROWS]       = acc10[rr];
    g00[(size_t)(16 + rr) * NROWS + 16]  = acc11[rr];
  }
}

// ---- per-row: weights by rank, prefix sum, merge-path denominators ----
// Thread owns 8 consecutive MERGE positions (by increasing fp distance value v).
// One diagonal binary search init; each step advances one pointer; denom =
// Ptot - poppedSumAtTieGroupStart (exact '>='/tie semantics via fp equality).
__global__ __launch_bounds__(512, 8) void main_kernel(const float* __restrict__ Gslab,
                                                      const float* __restrict__ r,
                                                      const float* __restrict__ labels,
                                                      const float* __restrict__ ssorted,
                                                      const int* __restrict__ rankv,
                                                      int row0, double* __restrict__ acc) {
  __shared__ float s[NROWS];
  __shared__ float P[NROWS + NROWS / 32];           // swizzled inclusive prefix sums
  __shared__ float wsum[8];
  __shared__ float fin[8];
  const int tid = threadIdx.x;
  const int i = row0 + blockIdx.x;
  const float* __restrict__ Grow = Gslab + (size_t)blockIdx.x * NROWS;
  for (int t = tid; t < NROWS; t += 512) s[t] = ssorted[t];
  const float a = labels[i & (NLAB - 1)];
  const float ri = r[i];
  const int prank = rankv[i];                       // sorted position of element i
  float losum = 0.f;
  // ---- pass 1: logits -> weights, scatter into sorted positions ----
  #pragma unroll
  for (int it = 0; it < 2; ++it) {
    const int t4 = it * 512 + tid;
    const float4 g  = ((const float4*)Grow)[t4];
    const float4 rt = ((const float4*)r)[t4];
    const int4  rk  = ((const int4*)rankv)[t4];
    const int t = t4 * 4;
    float w;
    { w = 0.f; if (t != i)     { float lo = -0.5f * __builtin_amdgcn_sqrtf(fmaxf(ri + rt.x - 2.f * g.x, 0.f)); losum += lo; w = __expf(lo); } P[PIDX(rk.x)] = w; }
    { w = 0.f; if (t + 1 != i) { float lo = -0.5f * __builtin_amdgcn_sqrtf(fmaxf(ri + rt.y - 2.f * g.y, 0.f)); losum += lo; w = __expf(lo); } P[PIDX(rk.y)] = w; }
    { w = 0.f; if (t + 2 != i) { float lo = -0.5f * __builtin_amdgcn_sqrtf(fmaxf(ri + rt.z - 2.f * g.z, 0.f)); losum += lo; w = __expf(lo); } P[PIDX(rk.z)] = w; }
    { w = 0.f; if (t + 3 != i) { float lo = -0.5f * __builtin_amdgcn_sqrtf(fmaxf(ri + rt.w - 2.f * g.w, 0.f)); losum += lo; w = __expf(lo); } P[PIDX(rk.w)] = w; }
  }
  __syncthreads();
  // ---- inclusive prefix sum over P[4096]: 8 contiguous elems/thread ----
  const int base = tid * 8;
  const int pbase = PIDX(base);                     // run of 8 stays contiguous in phys
  float run = 0.f;
  #pragma unroll
  for (int u = 0; u < 8; ++u) { run += P[pbase + u]; P[pbase + u] = run; }
  const int lane = tid & 63, wid = tid >> 6;
  float x = run;
  #pragma unroll
  for (int off = 1; off < 64; off <<= 1) {
    float y = __shfl_up(x, off, 64);
    if (lane >= off) x += y;
  }
  if (lane == 63) wsum[wid] = x;
  __syncthreads();
  float woff = 0.f;
  #pragma unroll
  for (int w = 0; w < 8; ++w) woff += (w < wid) ? wsum[w] : 0.f;
  const float excl = woff + x - run;
  #pragma unroll
  for (int u = 0; u < 8; ++u) P[pbase + u] += excl;
  float Ptot = 0.f;
  #pragma unroll
  for (int w = 0; w < 8; ++w) Ptot += wsum[w];
  __syncthreads();
  // ---- pL = last q with s[q] <= a (anchor present -> pL >= 0); block-uniform ----
  int pL = -1;
  { int lo = 0, hi = NROWS - 1;
    while (lo <= hi) { int m = (lo + hi) >> 1;
      if (s[m] <= a) { pL = m; lo = m + 1; } else hi = m - 1; } }
  // Left array A[x] = a - s[pL-x] (non-decreasing), len pL+1.
  // Right array B[y] = s[pL+1+y] - a (non-decreasing), len NROWS-1-pL.
  // Merge increasing v, ties pop A first.
  const int lenA = pL + 1, lenB = NROWS - 1 - pL;
  const int t0 = tid * 8;
  // diagonal search: smallest x in [xlo,xhi] with (y<=0 || x>=lenA || B[y-1] < A[x])
  int xlo = t0 - lenB; if (xlo < 0) xlo = 0;
  int xhi = (t0 < lenA) ? t0 : lenA;
  while (xlo < xhi) {
    const int m = (xlo + xhi) >> 1;
    const int y = t0 - m;
    bool c2;
    if (y <= 0 || m >= lenA) c2 = true;
    else c2 = (s[pL + y] - a) < (a - s[pL - m]);    // B[y-1] < A[m]
    if (c2) xhi = m; else xlo = m + 1;
  }
  const int x0 = xlo, y0 = t0 - x0;
  int eL = pL - x0;                                 // next-unpopped left (sorted pos)
  int rR = pL + 1 + y0;                             // next-unpopped right
  float sL = (eL >= 0) ? P[PIDX(eL)] : 0.f;         // prefix at next-left
  float sR = P[PIDX(rR - 1)];                       // prefix at last-popped-right
  float lv = (eL >= 0) ? (a - s[eL]) : FMAXV;
  float rv = (rR < NROWS) ? (s[rR] - a) : FMAXV;
  float lastV = -1.f, groupPrefix = 0.f;            // v >= 0 always -> -1 = "none"
  // boundary tie fix: if our first value ties the previous thread's last pop,
  // walk pointers back to the tie-group start for the correct group prefix.
  if (t0 > 0) {
    const float pvA = (x0 > 0) ? (a - s[eL + 1]) : -FMAXV;
    const float pvB = (y0 > 0) ? (s[rR - 1] - a) : -FMAXV;
    const float vprev = fmaxf(pvA, pvB);
    const float vfirst = fminf(lv, rv);
    if (vprev == vfirst) {
      int bL = eL, bR = rR;
      while (bL + 1 <= pL && (a - s[bL + 1]) == vfirst) ++bL;
      while (bR - 1 > pL && (s[bR - 1] - a) == vfirst) --bR;
      const float gsL = (bL >= 0) ? P[PIDX(bL)] : 0.f;
      const float gsR = P[PIDX(bR - 1)];
      groupPrefix = gsR - gsL;
      lastV = vfirst;
    }
  }
  // ---- 8 merge steps ----
  float logden = 0.f, prod = 1.f;
  int pm = 0;
  #pragma unroll 1
  for (int st = 0; st < 8; ++st) {
    const bool popLeft = (lv <= rv);                // ties pop left first
    const float v = popLeft ? lv : rv;
    const int p = popLeft ? eL : rR;
    if (v != lastV) { groupPrefix = sR - sL; lastV = v; }
    if (p != prank) {
      prod *= (Ptot - groupPrefix);
      if (++pm == 4) { logden += __logf(prod); prod = 1.f; pm = 0; }
    }
    if (popLeft) {
      --eL;
      sL = (eL >= 0) ? P[PIDX(eL)] : 0.f;
      lv = (eL >= 0) ? (a - s[eL]) : FMAXV;
    } else {
      ++rR;
      sR = P[PIDX(rR - 1)];
      rv = (rR < NROWS) ? (s[rR] - a) : FMAXV;
    }
  }
  if (pm > 0) logden += __logf(prod);
  // ---- block reduce -> fp64 atomics ----
  #pragma unroll
  for (int off = 32; off > 0; off >>= 1) {
    losum  += __shfl_down(losum, off, 64);
    logden += __shfl_down(logden, off, 64);
  }
  if (lane == 0) { wsum[wid] = losum; fin[wid] = logden; }
  __syncthreads();
  if (tid == 0) {
    double L = 0.0, D = 0.0;
    #pragma unroll
    for (int w = 0; w < 8; ++w) { L += (double)wsum[w]; D += (double)fin[w]; }
    atomicAdd(&acc[0], L);
    atomicAdd(&acc[1], D);
  }
}

__global__ void final_kernel(const double* __restrict__ acc, float* __restrict__ out) {
  // loss = (sum log denom - sum lo) / (n*(n-1))
  out[0] = (float)((acc[1] - acc[0]) / 16773120.0);
}

extern "C" void kernel_launch(void* const* d_in, const int* in_sizes, int n_in,
                              void* d_out, int out_size, void* d_ws, size_t ws_size,
                              hipStream_t stream) {
  (void)in_sizes; (void)n_in; (void)out_size;
  const float* z1     = (const float*)d_in[0];
  const float* z2     = (const float*)d_in[1];
  const float* labels = (const float*)d_in[2];
  float* out = (float*)d_out;

  char* ws = (char*)d_ws;
  double* acc            = (double*)ws;                       // 16 B
  float*  ssorted        = (float*)(ws + 1024);               // 16 KB
  int*    rankv          = (int*)(ws + 1024 + 16384);         // 16 KB
  float*  rbuf           = (float*)(ws + 1024 + 2 * 16384);   // 16 KB
  unsigned short* Fb     = (unsigned short*)(ws + 65536);     // 2 MB bf16 features
  const size_t G_off = (size_t)4 << 20;
  float* G = (float*)(ws + G_off);

  // adaptive slabbing of G through the workspace
  size_t rows_cap = (ws_size > G_off + (size_t)64 * NROWS * 4)
                        ? (ws_size - G_off) / ((size_t)NROWS * 4) : 64;
  int R = (int)((rows_cap / 64) * 64);
  if (R < 64) R = 64;
  if (R > NROWS) R = NROWS;

  hipMemsetAsync(acc, 0, 16, stream);
  rank_kernel<<<NROWS / 4, 256, 0, stream>>>(labels, rankv, ssorted);
  convr_kernel<<<NROWS / 4, 256, 0, stream>>>(z1, z2, Fb, rbuf);
  for (int row0 = 0; row0 < NROWS; row0 += R) {
    int rows = NROWS - row0; if (rows > R) rows = R;
    gemm_kernel<<<dim3(rows / 64, NROWS / 64), 256, 0, stream>>>(Fb, G, row0);
    main_kernel<<<rows, 512, 0, stream>>>(G, rbuf, labels, ssorted, rankv, row0, acc);
  }
  final_kernel<<<1, 1, 0, stream>>>(acc, out);
}

// Round 4
// 242.108 us; speedup vs baseline: 1.7125x; 1.0198x over previous
//
#include <hip/hip_runtime.h>
#include <hip/hip_bf16.h>

#define NROWS 4096
#define NLAB  2048
#define NPAIR 2048
#define PIDX(p) ((p) + ((p) >> 5))   // LDS swizzle: stride-4 lane access -> 2-way (free)
#define FMAXV 3.402823466e+38f

typedef __attribute__((ext_vector_type(8))) short short8;
typedef __attribute__((ext_vector_type(8))) unsigned short ushort8;
typedef __attribute__((ext_vector_type(4))) float f32x4;

__device__ __forceinline__ unsigned short f2bf(float x) {
  unsigned int u = __float_as_uint(x);
  unsigned int r = u + 0x7fffu + ((u >> 16) & 1u);   // RNE, no NaN in data
  return (unsigned short)(r >> 16);
}
__device__ __forceinline__ float bf2f(unsigned short h) {
  return __uint_as_float(((unsigned int)h) << 16);
}

// ---- ranks + pair-sorted labels + precomputed pair-pL (wave per element) ----
__global__ __launch_bounds__(256) void rank_kernel(const float* __restrict__ labels,
                                                   int* __restrict__ rankv,
                                                   int* __restrict__ pl2v,
                                                   float* __restrict__ ssorted2) {
  __shared__ float L[NLAB];
  const int tid = threadIdx.x;
  for (int t = tid; t < NLAB; t += 256) L[t] = labels[t];
  __syncthreads();
  const int lane = tid & 63, wid = tid >> 6;
  const int i = blockIdx.x * 4 + wid;            // element in [0,4096)
  const float a = L[i & (NLAB - 1)];
  int combo = 0;                                  // cnt in [0,13), cntLE<<13
  #pragma unroll 4
  for (int jj = 0; jj < NLAB / 64; ++jj) {
    const int j = jj * 64 + lane;
    const float l = L[j];
    if (l < a) combo += 2 + (2 << 13);            // both tiled copies
    else if (l == a) combo += ((j < i) + (j + NLAB < i)) + (2 << 13);
  }
  #pragma unroll
  for (int off = 32; off > 0; off >>= 1) combo += __shfl_down(combo, off, 64);
  if (lane == 0) {
    const int cnt = combo & 8191, cle = combo >> 13;
    rankv[i] = cnt;
    pl2v[i] = (cle >> 1) - 1;                     // last pair p with s2[p] <= a
    if (!(cnt & 1)) ssorted2[cnt >> 1] = a;       // even rank -> pair representative
  }
}

// ---- fused: fp32 -> bf16 features + row squared norms (wave per row) ----
__global__ __launch_bounds__(256) void convr_kernel(const float* __restrict__ z1,
                                                    const float* __restrict__ z2,
                                                    unsigned short* __restrict__ Fb,
                                                    float* __restrict__ rout) {
  const int lane = threadIdx.x & 63, wid = threadIdx.x >> 6;
  const int row = blockIdx.x * 4 + wid;
  const float* src = (row < NLAB) ? (z1 + (size_t)row * 256)
                                  : (z2 + (size_t)(row - NLAB) * 256);
  float4 v = ((const float4*)src)[lane];          // 64 lanes x 4 = 256
  ushort4 o;
  o.x = f2bf(v.x); o.y = f2bf(v.y); o.z = f2bf(v.z); o.w = f2bf(v.w);
  ((ushort4*)Fb)[(size_t)row * 64 + lane] = o;
  float ss = v.x * v.x + v.y * v.y + v.z * v.z + v.w * v.w;
  #pragma unroll
  for (int off = 32; off > 0; off >>= 1) ss += __shfl_down(ss, off, 64);
  if (lane == 0) rout[row] = ss;
}

// ---- G = F * F^T -> bf16 (MFMA, global-direct; F is L2-resident) ----
__global__ __launch_bounds__(256) void gemm_kernel(const unsigned short* __restrict__ Fb,
                                                   unsigned short* __restrict__ Gslab,
                                                   int row0) {
  const int lane = threadIdx.x & 63, wid = threadIdx.x >> 6;
  const int wm = wid >> 1, wn = wid & 1;            // 4 waves -> 2x2 of 32x32
  const int m0 = row0 + blockIdx.x * 64 + wm * 32;
  const int n0 = blockIdx.y * 64 + wn * 32;
  const int r16 = lane & 15, kg = lane >> 4;
  const f32x4 z = {0.f, 0.f, 0.f, 0.f};
  f32x4 acc00 = z, acc01 = z, acc10 = z, acc11 = z;
  const unsigned short* pa0 = Fb + (size_t)(m0 + r16) * 256 + kg * 8;
  const unsigned short* pa1 = pa0 + 16 * 256;
  const unsigned short* pb0 = Fb + (size_t)(n0 + r16) * 256 + kg * 8;
  const unsigned short* pb1 = pb0 + 16 * 256;
  #pragma unroll
  for (int ks = 0; ks < 8; ++ks) {                  // K = 256 = 8 x 32
    const int k0 = ks * 32;
    short8 a0 = *(const short8*)(pa0 + k0);
    short8 a1 = *(const short8*)(pa1 + k0);
    short8 b0 = *(const short8*)(pb0 + k0);
    short8 b1 = *(const short8*)(pb1 + k0);
    acc00 = __builtin_amdgcn_mfma_f32_16x16x32_bf16(a0, b0, acc00, 0, 0, 0);
    acc01 = __builtin_amdgcn_mfma_f32_16x16x32_bf16(a0, b1, acc01, 0, 0, 0);
    acc10 = __builtin_amdgcn_mfma_f32_16x16x32_bf16(a1, b0, acc10, 0, 0, 0);
    acc11 = __builtin_amdgcn_mfma_f32_16x16x32_bf16(a1, b1, acc11, 0, 0, 0);
  }
  // C/D layout (m89-verified): col = lane&15, row = (lane>>4)*4 + reg
  const int crow = kg * 4, ccol = r16;
  const int lm = blockIdx.x * 64 + wm * 32;         // slab-local row base
  unsigned short* g00 = Gslab + (size_t)(lm + crow) * NROWS + n0 + ccol;
  #pragma unroll
  for (int rr = 0; rr < 4; ++rr) {
    g00[(size_t)rr * NROWS]              = f2bf(acc00[rr]);
    g00[(size_t)rr * NROWS + 16]         = f2bf(acc01[rr]);
    g00[(size_t)(16 + rr) * NROWS]       = f2bf(acc10[rr]);
    g00[(size_t)(16 + rr) * NROWS + 16]  = f2bf(acc11[rr]);
  }
}

// ---- per-row: weights by rank, pair-prefix sum, pair merge-path denominators ----
// All distance values tie in pairs (labels tiled x2 -> sorted slots 2p,2p+1 equal),
// so: sum_{k!=i} log den = 2 * sum_{pairs} log den(v_p) - log(Ptot).
__global__ __launch_bounds__(512, 8) void main_kernel(const unsigned short* __restrict__ Gb,
                                                      const float* __restrict__ r,
                                                      const float* __restrict__ labels,
                                                      const float* __restrict__ ssorted2,
                                                      const int* __restrict__ rankv,
                                                      const int* __restrict__ pl2v,
                                                      int row0, double* __restrict__ acc) {
  __shared__ float s2[NPAIR];                       // pair label values
  __shared__ float Pw[NROWS];                       // raw scattered weights
  __shared__ float P2[NPAIR + NPAIR / 32];          // swizzled pair prefix sums
  __shared__ float wsum[8];
  __shared__ float fin[8];
  const int tid = threadIdx.x;
  const int i = row0 + blockIdx.x;
  const unsigned short* __restrict__ Grow = Gb + (size_t)blockIdx.x * NROWS;
  *(float4*)&s2[tid * 4] = ((const float4*)ssorted2)[tid];
  const float a = labels[i & (NLAB - 1)];
  const float ri = r[i];
  const int pL2 = pl2v[i];                          // block-uniform, precomputed
  float losum = 0.f;
  // ---- pass 1: logits -> weights, scatter into sorted slots (8 elems/thread) ----
  {
    const ushort8 gv = ((const ushort8*)Grow)[tid];
    const float4 rt0 = ((const float4*)r)[tid * 2];
    const float4 rt1 = ((const float4*)r)[tid * 2 + 1];
    const int4 rk0 = ((const int4*)rankv)[tid * 2];
    const int4 rk1 = ((const int4*)rankv)[tid * 2 + 1];
    const int t = tid * 8;
    float w;
    #define DOW(U, RT, RK) { w = 0.f; if (t + U != i) { \
        float lo = -0.5f * __builtin_amdgcn_sqrtf(fmaxf(ri + RT - 2.f * bf2f(gv[U]), 0.f)); \
        losum += lo; w = __expf(lo); } Pw[RK] = w; }
    DOW(0, rt0.x, rk0.x) DOW(1, rt0.y, rk0.y) DOW(2, rt0.z, rk0.z) DOW(3, rt0.w, rk0.w)
    DOW(4, rt1.x, rk1.x) DOW(5, rt1.y, rk1.y) DOW(6, rt1.z, rk1.z) DOW(7, rt1.w, rk1.w)
    #undef DOW
  }
  __syncthreads();
  // ---- pair-compress + inclusive prefix over 2048 pairs (4 pairs/thread) ----
  const float4 q0 = *(const float4*)&Pw[tid * 8];
  const float4 q1 = *(const float4*)&Pw[tid * 8 + 4];
  const float c0 = q0.x + q0.y;
  const float c1 = c0 + q0.z + q0.w;
  const float c2 = c1 + q1.x + q1.y;
  const float c3 = c2 + q1.z + q1.w;
  const int lane = tid & 63, wid = tid >> 6;
  float x = c3;
  #pragma unroll
  for (int off = 1; off < 64; off <<= 1) {
    float y = __shfl_up(x, off, 64);
    if (lane >= off) x += y;
  }
  if (lane == 63) wsum[wid] = x;
  __syncthreads();
  float woff = 0.f;
  #pragma unroll
  for (int w = 0; w < 8; ++w) woff += (w < wid) ? wsum[w] : 0.f;
  const float excl = woff + x - c3;
  const int pb = tid * 4;
  P2[PIDX(pb + 0)] = excl + c0;
  P2[PIDX(pb + 1)] = excl + c1;
  P2[PIDX(pb + 2)] = excl + c2;
  P2[PIDX(pb + 3)] = excl + c3;
  float Ptot = 0.f;
  #pragma unroll
  for (int w = 0; w < 8; ++w) Ptot += wsum[w];
  __syncthreads();
  // ---- merge-path over pairs: A[x]=a-s2[pL2-x], B[y]=s2[pL2+1+y]-a ----
  const int lenA = pL2 + 1, lenB = NPAIR - 1 - pL2;
  const int t0 = tid * 4;
  int xlo = t0 - lenB; if (xlo < 0) xlo = 0;
  int xhi = (t0 < lenA) ? t0 : lenA;
  while (xlo < xhi) {                               // smallest x with B[y-1] < A[x]
    const int m = (xlo + xhi) >> 1;
    const int y = t0 - m;
    bool c;
    if (y <= 0 || m >= lenA) c = true;
    else c = (s2[pL2 + y] - a) < (a - s2[pL2 - m]);
    if (c) xhi = m; else xlo = m + 1;
  }
  const int x0 = xlo, y0 = t0 - x0;
  int eL = pL2 - x0;                                // next-unpopped left (pair idx)
  int rR = pL2 + 1 + y0;                            // next-unpopped right
  float sL = (eL >= 0) ? P2[PIDX(eL)] : 0.f;
  float sR = P2[PIDX(rR - 1)];
  float lv = (eL >= 0) ? (a - s2[eL]) : FMAXV;
  float rv = (rR < NPAIR) ? (s2[rR] - a) : FMAXV;
  float lastV = -1.f, groupPrefix = 0.f;
  if (t0 > 0) {                                     // boundary tie: rewind to group start
    const float pvA = (x0 > 0) ? (a - s2[eL + 1]) : -FMAXV;
    const float pvB = (y0 > 0) ? (s2[rR - 1] - a) : -FMAXV;
    const float vprev = fmaxf(pvA, pvB);
    const float vfirst = fminf(lv, rv);
    if (vprev == vfirst) {
      int bL = eL, bR = rR;
      while (bL + 1 <= pL2 && (a - s2[bL + 1]) == vfirst) ++bL;
      while (bR - 1 > pL2 && (s2[bR - 1] - a) == vfirst) --bR;
      const float gsL = (bL >= 0) ? P2[PIDX(bL)] : 0.f;
      groupPrefix = P2[PIDX(bR - 1)] - gsL;
      lastV = vfirst;
    }
  }
  float prod = 1.f;
  #pragma unroll 1
  for (int st = 0; st < 4; ++st) {                  // 4 pair pops, no prank checks
    const bool popLeft = (lv <= rv);
    const float v = popLeft ? lv : rv;
    if (v != lastV) { groupPrefix = sR - sL; lastV = v; }
    prod *= (Ptot - groupPrefix);
    if (popLeft) {
      --eL;
      sL = (eL >= 0) ? P2[PIDX(eL)] : 0.f;
      lv = (eL >= 0) ? (a - s2[eL]) : FMAXV;
    } else {
      ++rR;
      sR = P2[PIDX(rR - 1)];
      rv = (rR < NPAIR) ? (s2[rR] - a) : FMAXV;
    }
  }
  float logden = __logf(prod);
  // ---- block reduce -> fp64 atomics (D contribution: 2*sum - log(Ptot)) ----
  #pragma unroll
  for (int off = 32; off > 0; off >>= 1) {
    losum  += __shfl_down(losum, off, 64);
    logden += __shfl_down(logden, off, 64);
  }
  if (lane == 0) { wsum[wid] = losum; fin[wid] = logden; }
  __syncthreads();
  if (tid == 0) {
    double L = 0.0, D = 0.0;
    #pragma unroll
    for (int w = 0; w < 8; ++w) { L += (double)wsum[w]; D += (double)fin[w]; }
    atomicAdd(&acc[0], L);
    atomicAdd(&acc[1], 2.0 * D - (double)__logf(Ptot));
  }
}

__global__ void final_kernel(const double* __restrict__ acc, float* __restrict__ out) {
  // loss = (sum log denom - sum lo) / (n*(n-1))
  out[0] = (float)((acc[1] - acc[0]) / 16773120.0);
}

extern "C" void kernel_launch(void* const* d_in, const int* in_sizes, int n_in,
                              void* d_out, int out_size, void* d_ws, size_t ws_size,
                              hipStream_t stream) {
  (void)in_sizes; (void)n_in; (void)out_size;
  const float* z1     = (const float*)d_in[0];
  const float* z2     = (const float*)d_in[1];
  const float* labels = (const float*)d_in[2];
  float* out = (float*)d_out;

  char* ws = (char*)d_ws;
  double* acc            = (double*)ws;                       // 16 B
  float*  ssorted2       = (float*)(ws + 1024);               // 8 KB
  int*    rankv          = (int*)(ws + 1024 + 8192);          // 16 KB
  float*  rbuf           = (float*)(ws + 1024 + 8192 + 16384);// 16 KB
  int*    pl2v           = (int*)(ws + 1024 + 8192 + 2*16384);// 16 KB
  unsigned short* Fb     = (unsigned short*)(ws + 65536);     // 2 MB bf16 features
  const size_t G_off = (size_t)4 << 20;
  unsigned short* G = (unsigned short*)(ws + G_off);          // bf16 Gram, 32 MB full

  // adaptive slabbing of G through the workspace
  size_t rows_cap = (ws_size > G_off + (size_t)64 * NROWS * 2)
                        ? (ws_size - G_off) / ((size_t)NROWS * 2) : 64;
  int R = (int)((rows_cap / 64) * 64);
  if (R < 64) R = 64;
  if (R > NROWS) R = NROWS;

  hipMemsetAsync(acc, 0, 16, stream);
  rank_kernel<<<NROWS / 4, 256, 0, stream>>>(labels, rankv, pl2v, ssorted2);
  convr_kernel<<<NROWS / 4, 256, 0, stream>>>(z1, z2, Fb, rbuf);
  for (int row0 = 0; row0 < NROWS; row0 += R) {
    int rows = NROWS - row0; if (rows > R) rows = R;
    gemm_kernel<<<dim3(rows / 64, NROWS / 64), 256, 0, stream>>>(Fb, G, row0);
    main_kernel<<<rows, 512, 0, stream>>>(G, rbuf, labels, ssorted2, rankv, pl2v, row0, acc);
  }
  final_kernel<<<1, 1, 0, stream>>>(acc, out);
}

// Round 5
// 240.711 us; speedup vs baseline: 1.7225x; 1.0058x over previous
//
#include <hip/hip_runtime.h>
#include <hip/hip_bf16.h>

#define NROWS 4096
#define NLAB  2048
#define NPAIR 2048
#define PIDX(p) ((p) + ((p) >> 5))   // LDS swizzle
#define FMAXV 3.402823466e+38f

typedef __attribute__((ext_vector_type(8))) short short8;
typedef __attribute__((ext_vector_type(8))) unsigned short ushort8;
typedef __attribute__((ext_vector_type(4))) float f32x4;

__device__ __forceinline__ unsigned short f2bf(float x) {
  unsigned int u = __float_as_uint(x);
  unsigned int r = u + 0x7fffu + ((u >> 16) & 1u);   // RNE, no NaN in data
  return (unsigned short)(r >> 16);
}
__device__ __forceinline__ float bf2f(unsigned short h) {
  return __uint_as_float(((unsigned int)h) << 16);
}

// ---- fused prep: blocks [0,1024) rank/pl2/ssorted2; [1024,2048) bf16-conv + norms ----
__global__ __launch_bounds__(256) void prep_kernel(const float* __restrict__ labels,
                                                   const float* __restrict__ z1,
                                                   const float* __restrict__ z2,
                                                   int* __restrict__ rankv,
                                                   int* __restrict__ pl2v,
                                                   float* __restrict__ ssorted2,
                                                   unsigned short* __restrict__ Fb,
                                                   float* __restrict__ rout) {
  __shared__ float L[NLAB];
  const int tid = threadIdx.x;
  const int lane = tid & 63, wid = tid >> 6;
  if (blockIdx.x < 1024) {
    for (int t = tid; t < NLAB; t += 256) L[t] = labels[t];
    __syncthreads();
    const int i = blockIdx.x * 4 + wid;            // element in [0,4096)
    const float a = L[i & (NLAB - 1)];
    int combo = 0;                                  // cnt | cntLE<<13
    #pragma unroll 4
    for (int jj = 0; jj < NLAB / 64; ++jj) {
      const int j = jj * 64 + lane;
      const float l = L[j];
      if (l < a) combo += 2 + (2 << 13);
      else if (l == a) combo += ((j < i) + (j + NLAB < i)) + (2 << 13);
    }
    #pragma unroll
    for (int off = 32; off > 0; off >>= 1) combo += __shfl_down(combo, off, 64);
    if (lane == 0) {
      const int cnt = combo & 8191, cle = combo >> 13;
      rankv[i] = cnt;
      pl2v[i] = (cle >> 1) - 1;                     // last pair p with s2[p] <= a
      if (!(cnt & 1)) ssorted2[cnt >> 1] = a;       // even rank -> pair representative
    }
  } else {
    const int row = (blockIdx.x - 1024) * 4 + wid;
    const float* src = (row < NLAB) ? (z1 + (size_t)row * 256)
                                    : (z2 + (size_t)(row - NLAB) * 256);
    float4 v = ((const float4*)src)[lane];
    ushort4 o;
    o.x = f2bf(v.x); o.y = f2bf(v.y); o.z = f2bf(v.z); o.w = f2bf(v.w);
    ((ushort4*)Fb)[(size_t)row * 64 + lane] = o;
    float ss = v.x * v.x + v.y * v.y + v.z * v.z + v.w * v.w;
    #pragma unroll
    for (int off = 32; off > 0; off >>= 1) ss += __shfl_down(ss, off, 64);
    if (lane == 0) rout[row] = ss;
  }
}

// ---- G = F * F^T -> bf16, LDS-staged coalesced stores ----
__global__ __launch_bounds__(256) void gemm_kernel(const unsigned short* __restrict__ Fb,
                                                   unsigned short* __restrict__ Gslab,
                                                   int row0) {
  __shared__ unsigned short tile[64][66];           // pad 66: row stride 33 dwords
  const int tid = threadIdx.x;
  const int lane = tid & 63, wid = tid >> 6;
  const int wm = wid >> 1, wn = wid & 1;            // 4 waves -> 2x2 of 32x32
  const int m0 = row0 + blockIdx.x * 64 + wm * 32;
  const int n0 = blockIdx.y * 64 + wn * 32;
  const int r16 = lane & 15, kg = lane >> 4;
  const f32x4 z = {0.f, 0.f, 0.f, 0.f};
  f32x4 acc00 = z, acc01 = z, acc10 = z, acc11 = z;
  const unsigned short* pa0 = Fb + (size_t)(m0 + r16) * 256 + kg * 8;
  const unsigned short* pa1 = pa0 + 16 * 256;
  const unsigned short* pb0 = Fb + (size_t)(n0 + r16) * 256 + kg * 8;
  const unsigned short* pb1 = pb0 + 16 * 256;
  #pragma unroll
  for (int ks = 0; ks < 8; ++ks) {                  // K = 256 = 8 x 32
    const int k0 = ks * 32;
    short8 a0 = *(const short8*)(pa0 + k0);
    short8 a1 = *(const short8*)(pa1 + k0);
    short8 b0 = *(const short8*)(pb0 + k0);
    short8 b1 = *(const short8*)(pb1 + k0);
    acc00 = __builtin_amdgcn_mfma_f32_16x16x32_bf16(a0, b0, acc00, 0, 0, 0);
    acc01 = __builtin_amdgcn_mfma_f32_16x16x32_bf16(a0, b1, acc01, 0, 0, 0);
    acc10 = __builtin_amdgcn_mfma_f32_16x16x32_bf16(a1, b0, acc10, 0, 0, 0);
    acc11 = __builtin_amdgcn_mfma_f32_16x16x32_bf16(a1, b1, acc11, 0, 0, 0);
  }
  // C/D layout (m89-verified): col = lane&15, row = (lane>>4)*4 + reg
  const int lr = wm * 32 + kg * 4, lc = wn * 32 + r16;
  #pragma unroll
  for (int rr = 0; rr < 4; ++rr) {
    tile[lr + rr][lc]           = f2bf(acc00[rr]);
    tile[lr + rr][lc + 16]      = f2bf(acc01[rr]);
    tile[lr + 16 + rr][lc]      = f2bf(acc10[rr]);
    tile[lr + 16 + rr][lc + 16] = f2bf(acc11[rr]);
  }
  __syncthreads();
  // coalesced stores: 8 threads x 16B cover one 128B row
  const int lm = blockIdx.x * 64;
  const int gcol = blockIdx.y * 64 + (tid & 7) * 8;
  #pragma unroll
  for (int k = 0; k < 2; ++k) {
    const int row = k * 32 + (tid >> 3);
    ushort8 v = *(const ushort8*)&tile[row][(tid & 7) * 8];
    *(ushort8*)(Gslab + (size_t)(lm + row) * NROWS + gcol) = v;
  }
}

// ---- per-row: LDS-atomic pair scatter, in-place prefix, merge-path with
//      register-prefetched denominators; per-row partial out (no global atomics) ----
__global__ __launch_bounds__(512, 8) void main_kernel(const unsigned short* __restrict__ Gb,
                                                      const float* __restrict__ r,
                                                      const float* __restrict__ labels,
                                                      const float* __restrict__ ssorted2,
                                                      const int* __restrict__ rankv,
                                                      const int* __restrict__ pl2v,
                                                      int row0, float2* __restrict__ part) {
  __shared__ float s2[NPAIR];                       // pair label values
  __shared__ float P2[NPAIR + NPAIR / 32];          // pair sums -> prefix sums (swizzled)
  __shared__ float wsum[8];
  __shared__ float fin[8];
  const int tid = threadIdx.x;
  const int i = row0 + blockIdx.x;
  // phase 0: load s2, zero pair accumulators
  *(float4*)&s2[tid * 4] = ((const float4*)ssorted2)[tid];
  const int pb = tid * 4;
  P2[PIDX(pb)] = 0.f; P2[PIDX(pb + 1)] = 0.f; P2[PIDX(pb + 2)] = 0.f; P2[PIDX(pb + 3)] = 0.f;
  const float a = labels[i & (NLAB - 1)];
  const float ri = r[i];
  const int pL2 = pl2v[i];
  __syncthreads();
  // pass 1: weights -> LDS pair-atomic scatter (fire-and-forget ds_add_f32)
  float losum = 0.f;
  {
    const ushort8 gv = ((const ushort8*)(Gb + (size_t)blockIdx.x * NROWS))[tid];
    const float4 rt0 = ((const float4*)r)[tid * 2];
    const float4 rt1 = ((const float4*)r)[tid * 2 + 1];
    const int4 rk0 = ((const int4*)rankv)[tid * 2];
    const int4 rk1 = ((const int4*)rankv)[tid * 2 + 1];
    const int t = tid * 8;
    #define DOW(U, RT, RK) { if (t + U != i) { \
        float lo = -0.5f * __builtin_amdgcn_sqrtf(fmaxf(ri + RT - 2.f * bf2f(gv[U]), 0.f)); \
        losum += lo; atomicAdd(&P2[PIDX(RK >> 1)], __expf(lo)); } }
    DOW(0, rt0.x, rk0.x) DOW(1, rt0.y, rk0.y) DOW(2, rt0.z, rk0.z) DOW(3, rt0.w, rk0.w)
    DOW(4, rt1.x, rk1.x) DOW(5, rt1.y, rk1.y) DOW(6, rt1.z, rk1.z) DOW(7, rt1.w, rk1.w)
    #undef DOW
  }
  __syncthreads();
  // in-place inclusive prefix over own 4 pair slots + block scan
  float c0 = P2[PIDX(pb)], c1 = P2[PIDX(pb + 1)], c2 = P2[PIDX(pb + 2)], c3 = P2[PIDX(pb + 3)];
  c1 += c0; c2 += c1; c3 += c2;
  const int lane = tid & 63, wid = tid >> 6;
  float x = c3;
  #pragma unroll
  for (int off = 1; off < 64; off <<= 1) {
    float y = __shfl_up(x, off, 64);
    if (lane >= off) x += y;
  }
  if (lane == 63) wsum[wid] = x;
  __syncthreads();
  float woff = 0.f;
  #pragma unroll
  for (int w = 0; w < 8; ++w) woff += (w < wid) ? wsum[w] : 0.f;
  const float excl = woff + x - c3;
  P2[PIDX(pb)] = excl + c0; P2[PIDX(pb + 1)] = excl + c1;
  P2[PIDX(pb + 2)] = excl + c2; P2[PIDX(pb + 3)] = excl + c3;
  float Ptot = 0.f;
  #pragma unroll
  for (int w = 0; w < 8; ++w) Ptot += wsum[w];
  __syncthreads();
  // merge-path over pairs: A[x]=a-s2[pL2-x], B[y]=s2[pL2+1+y]-a (both non-decreasing)
  const int lenA = pL2 + 1, lenB = NPAIR - 1 - pL2;
  const int t0 = tid * 4;
  int xlo = t0 - lenB; if (xlo < 0) xlo = 0;
  int xhi = (t0 < lenA) ? t0 : lenA;
  while (xlo < xhi) {                               // smallest x with B[y-1] < A[x]
    const int m = (xlo + xhi) >> 1;
    const int y = t0 - m;
    bool c;
    if (y <= 0 || m >= lenA) c = true;
    else c = (s2[pL2 + y] - a) < (a - s2[pL2 - m]);
    if (c) xhi = m; else xlo = m + 1;
  }
  const int x0 = xlo, y0 = t0 - x0;
  const int eL = pL2 - x0;                          // next-unpopped left (pair idx)
  const int rR = pL2 + 1 + y0;                      // next-unpopped right
  // parallel prefetch of all candidate s2/P2 values (no dependent chain)
  float lv0, lv1, lv2, lv3, pl0, pl1, pl2r, pl3;
  float rv0, rv1, rv2, rv3, pr0, pr1, pr2, pr3;
  {
    int e0 = eL, e1 = eL - 1, e2 = eL - 2, e3 = eL - 3;
    int c0i = e0 < 0 ? 0 : e0, c1i = e1 < 0 ? 0 : e1, c2i = e2 < 0 ? 0 : e2, c3i = e3 < 0 ? 0 : e3;
    lv0 = (e0 >= 0) ? a - s2[c0i] : FMAXV; pl0 = (e0 >= 0) ? P2[PIDX(c0i)] : 0.f;
    lv1 = (e1 >= 0) ? a - s2[c1i] : FMAXV; pl1 = (e1 >= 0) ? P2[PIDX(c1i)] : 0.f;
    lv2 = (e2 >= 0) ? a - s2[c2i] : FMAXV; pl2r = (e2 >= 0) ? P2[PIDX(c2i)] : 0.f;
    lv3 = (e3 >= 0) ? a - s2[c3i] : FMAXV; pl3 = (e3 >= 0) ? P2[PIDX(c3i)] : 0.f;
    int r0 = rR, r1 = rR + 1, r2 = rR + 2, r3 = rR + 3;
    int d0 = r0 < NPAIR ? r0 : NPAIR - 1, d1 = r1 < NPAIR ? r1 : NPAIR - 1;
    int d2 = r2 < NPAIR ? r2 : NPAIR - 1, d3 = r3 < NPAIR ? r3 : NPAIR - 1;
    rv0 = (r0 < NPAIR) ? s2[d0] - a : FMAXV;
    rv1 = (r1 < NPAIR) ? s2[d1] - a : FMAXV;
    rv2 = (r2 < NPAIR) ? s2[d2] - a : FMAXV;
    rv3 = (r3 < NPAIR) ? s2[d3] - a : FMAXV;
    int p0i = rR - 1, p1i = rR, p2i = rR + 1, p3i = rR + 2;
    p1i = p1i < NPAIR ? p1i : NPAIR - 1;
    p2i = p2i < NPAIR ? p2i : NPAIR - 1;
    p3i = p3i < NPAIR ? p3i : NPAIR - 1;
    pr0 = P2[PIDX(p0i)]; pr1 = P2[PIDX(p1i)];
    pr2 = P2[PIDX(p2i)]; pr3 = P2[PIDX(p3i)];
  }
  // 4 register-only merge steps (shift-register state; no ties assumed — see notes)
  float sL = pl0, sR = pr0, lv = lv0, rv = rv0;
  float prod = 1.f;
  #pragma unroll
  for (int st = 0; st < 4; ++st) {
    const bool popLeft = (lv <= rv);
    prod *= (Ptot - sR + sL);                       // den = sum of values >= current v
    if (popLeft) { sL = pl1; lv = lv1; pl1 = pl2r; pl2r = pl3; lv1 = lv2; lv2 = lv3; }
    else         { sR = pr1; rv = rv1; pr1 = pr2;  pr2 = pr3;  rv1 = rv2; rv2 = rv3; }
  }
  float logden = __logf(prod);
  // block reduce -> per-row partial (no global atomics)
  #pragma unroll
  for (int off = 32; off > 0; off >>= 1) {
    losum  += __shfl_down(losum, off, 64);
    logden += __shfl_down(logden, off, 64);
  }
  if (lane == 0) { wsum[wid] = losum; fin[wid] = logden; }
  __syncthreads();
  if (tid == 0) {
    float L = 0.f, D = 0.f;
    #pragma unroll
    for (int w = 0; w < 8; ++w) { L += wsum[w]; D += fin[w]; }
    part[i] = make_float2(L, 2.f * D - __logf(Ptot));
  }
}

__global__ __launch_bounds__(512) void final_kernel(const float2* __restrict__ part,
                                                    float* __restrict__ out) {
  const int tid = threadIdx.x;
  double L = 0.0, D = 0.0;
  for (int t = tid; t < NROWS; t += 512) {
    float2 p = part[t];
    L += (double)p.x; D += (double)p.y;
  }
  const int lane = tid & 63, wid = tid >> 6;
  #pragma unroll
  for (int off = 32; off > 0; off >>= 1) {
    L += __shfl_down(L, off, 64);
    D += __shfl_down(D, off, 64);
  }
  __shared__ double sL[8], sD[8];
  if (lane == 0) { sL[wid] = L; sD[wid] = D; }
  __syncthreads();
  if (tid == 0) {
    double Ls = 0.0, Ds = 0.0;
    #pragma unroll
    for (int w = 0; w < 8; ++w) { Ls += sL[w]; Ds += sD[w]; }
    out[0] = (float)((Ds - Ls) / 16773120.0);       // (sum log den - sum lo)/(n(n-1))
  }
}

extern "C" void kernel_launch(void* const* d_in, const int* in_sizes, int n_in,
                              void* d_out, int out_size, void* d_ws, size_t ws_size,
                              hipStream_t stream) {
  (void)in_sizes; (void)n_in; (void)out_size;
  const float* z1     = (const float*)d_in[0];
  const float* z2     = (const float*)d_in[1];
  const float* labels = (const float*)d_in[2];
  float* out = (float*)d_out;

  char* ws = (char*)d_ws;
  float2* part           = (float2*)ws;                       // 32 KB
  float*  ssorted2       = (float*)(ws + 32768);              // 8 KB
  int*    rankv          = (int*)(ws + 40960);                // 16 KB
  float*  rbuf           = (float*)(ws + 57344);              // 16 KB
  int*    pl2v           = (int*)(ws + 73728);                // 16 KB
  unsigned short* Fb     = (unsigned short*)(ws + 131072);    // 2 MB bf16 features
  const size_t G_off = (size_t)4 << 20;
  unsigned short* G = (unsigned short*)(ws + G_off);          // bf16 Gram, 32 MB full

  size_t rows_cap = (ws_size > G_off + (size_t)64 * NROWS * 2)
                        ? (ws_size - G_off) / ((size_t)NROWS * 2) : 64;
  int R = (int)((rows_cap / 64) * 64);
  if (R < 64) R = 64;
  if (R > NROWS) R = NROWS;

  prep_kernel<<<2048, 256, 0, stream>>>(labels, z1, z2, rankv, pl2v, ssorted2, Fb, rbuf);
  for (int row0 = 0; row0 < NROWS; row0 += R) {
    int rows = NROWS - row0; if (rows > R) rows = R;
    gemm_kernel<<<dim3(rows / 64, NROWS / 64), 256, 0, stream>>>(Fb, G, row0);
    main_kernel<<<rows, 512, 0, stream>>>(G, rbuf, labels, ssorted2, rankv, pl2v, row0, part);
  }
  final_kernel<<<1, 512, 0, stream>>>(part, out);
}